// Round 6
// baseline (109.332 us; speedup 1.0000x reference)
//
#include <hip/hip_runtime.h>
#include <hip/hip_bf16.h>
#include <math.h>

// Problem dims (fixed)
#define BB 4
#define TT 4096
#define DM 1024
#define DS 256
#define MROWS (BB*TT)        // 16384

// Scan chunking
#define LCH 32
#define NCH (TT/LCH)         // 128

#define BK 32
#define BM 128

typedef __attribute__((ext_vector_type(8))) short short8v;
typedef __attribute__((ext_vector_type(8))) unsigned short ushort8v;
typedef __attribute__((ext_vector_type(4))) float float4v;

__device__ __forceinline__ unsigned short bf16_bits(float f) {
    union { __hip_bfloat16 b; unsigned short u; } cv;
    cv.b = __float2bfloat16(f);
    return cv.u;
}
__device__ __forceinline__ float bits_to_f32(unsigned short h) {
    union { unsigned int u; float f; } cv; cv.u = ((unsigned int)h) << 16; return cv.f;
}
__device__ __forceinline__ void split_bf16(float a, unsigned short& hi, unsigned short& lo) {
    hi = bf16_bits(a);
    lo = bf16_bits(a - bits_to_f32(hi));
}
__device__ __forceinline__ float sigmoidf_dev(float x) {
    return 1.0f / (1.0f + expf(-x));
}

// async global->LDS, 16 bytes per lane; dest must be uniform + lane*16 (m104)
__device__ __forceinline__ void gload16(const void* g, void* l) {
    __builtin_amdgcn_global_load_lds(
        (const __attribute__((address_space(1))) void*)g,
        (__attribute__((address_space(3))) void*)l, 16, 0, 0);
}

// ---------------- weight pre-split (both weights in one launch) ----------------
// W[K][N] fp32 -> {hi,lo}[N][K] bf16 (transposed)
__global__ __launch_bounds__(256) void split_weights(
    const float* __restrict__ W1, unsigned short* __restrict__ B1h, unsigned short* __restrict__ B1l,
    const float* __restrict__ W2, unsigned short* __restrict__ B2h, unsigned short* __restrict__ B2l)
{
    const int half = blockIdx.x >> 10;            // 0: W_in, 1: W_out (1024 blocks each)
    int idx = (blockIdx.x & 1023) * 256 + threadIdx.x;   // over N*K = 262144
    const float* W = half ? W2 : W1;
    unsigned short* Bh = half ? B2h : B1h;
    unsigned short* Bl = half ? B2l : B1l;
    const int K = half ? DS : DM;
    const int N = half ? DM : DS;
    int n = idx / K, k = idx - n * K;
    float a = W[(size_t)k * N + n];
    unsigned short hi, lo;
    split_bf16(a, hi, lo);
    Bh[idx] = hi;
    Bl[idx] = lo;
}

// ---------------- x pre-split: fp32 [M][K] -> bf16 hi/lo [M][K] ----------------
__global__ __launch_bounds__(256) void split_x(
    const float* __restrict__ x, unsigned short* __restrict__ xh, unsigned short* __restrict__ xl)
{
    size_t u = (size_t)blockIdx.x * 256 + threadIdx.x;    // unit = 8 elems
    const float* p = x + u * 8;
    float4 a = *(const float4*)p;
    float4 b = *(const float4*)(p + 4);
    float f[8] = {a.x, a.y, a.z, a.w, b.x, b.y, b.z, b.w};
    ushort8v h, l;
#pragma unroll
    for (int e = 0; e < 8; e++) {
        unsigned short hu, lu;
        split_bf16(f[e], hu, lu);
        h[e] = hu; l[e] = lu;
    }
    *(ushort8v*)(xh + u * 8) = h;
    *(ushort8v*)(xl + u * 8) = l;
}

// ---------------- split-bf16 MFMA GEMM (m97 structure, presplit A) ----------------
// C[M][N] = (A[M][K] @ Bt[N][K]^T + bias[n]) * scale[n]
// 256 threads, 4 waves 2x2. Wave tile: 64 x (BN/2).
// FUSE: also compute per-chunk scan partials csum from the output tile
// (requires BM=128 rows aligned to LCH=32 chunks, BN=64).
// Swizzle (pre-swizzled global source, same XOR on LDS read; LDS dest linear):
//   bf16 tiles [rows][4 chunks16B]: chunk' = chunk ^ ((row>>1)&3)  -> 2-way max
template<int BN, bool FUSE>
__global__ __launch_bounds__(256) void mfma_gemm(
    const unsigned short* __restrict__ Ahg, const unsigned short* __restrict__ Alg,
    const unsigned short* __restrict__ Bhg, const unsigned short* __restrict__ Blg,
    float* __restrict__ C, int M, int N, int K, int GN,
    const float* __restrict__ bias, const float* __restrict__ scale,
    const float* __restrict__ lam, float* __restrict__ csum)
{
    constexpr int BHALF = BN * 64;                 // bytes of one B half (hi or lo)
    constexpr int BUFB  = 16384 + 2 * BHALF;       // bytes per pipeline buffer
    constexpr int NF    = BN / 32;                 // B frags per wave
    constexpr int SMSZ  = (2 * BUFB > 34816) ? 2 * BUFB : 34816;
    __shared__ char smem[SMSZ];

    // XCD-aware block swizzle (grid % 8 == 0)
    const int nwg = gridDim.x;
    const int bid = blockIdx.x;
    const int wgid = (bid & 7) * (nwg >> 3) + (bid >> 3);
    const int bm = wgid / GN;
    const int bn = wgid - bm * GN;

    const int tid  = threadIdx.x;
    const int lane = tid & 63;
    const int wv   = tid >> 6;
    const int wr   = wv >> 1;            // wave row: 0..1 (64 rows)
    const int wc   = wv & 1;             // wave col: 0..1 (BN/2 cols)
    const int lrow = lane & 15;
    const int q16  = lane >> 4;          // 0..3

    const int NT = K / BK;
    float4v acc[4][NF] = {};

#define STAGE(T, Q)                                                               \
    do {                                                                          \
        const int k0_ = (T) * BK;                                                 \
        char* base_ = smem + (Q) * BUFB;                                          \
        _Pragma("unroll")                                                         \
        for (int p = 0; p < 2; p++) {                                             \
            int c = tid + p * 256, row = c >> 2, cc = c & 3;                      \
            size_t go = (size_t)(bm * BM + row) * K + k0_                         \
                        + ((cc ^ ((row >> 1) & 3)) << 3);                         \
            gload16(Ahg + go, base_ + c * 16);                                    \
            gload16(Alg + go, base_ + 8192 + c * 16);                             \
        }                                                                         \
        _Pragma("unroll")                                                         \
        for (int p = 0; p < BN / 64; p++) {                                       \
            int c = tid + p * 256, row = c >> 2, cc = c & 3;                      \
            size_t go = (size_t)(bn * BN + row) * K + k0_                         \
                        + ((cc ^ ((row >> 1) & 3)) << 3);                         \
            gload16(Bhg + go, base_ + 16384 + c * 16);                            \
            gload16(Blg + go, base_ + 16384 + BHALF + c * 16);                    \
        }                                                                         \
    } while (0)

    STAGE(0, 0);
    __syncthreads();

    for (int t = 0; t < NT; ++t) {
        const int Q = t & 1;
        if (t + 1 < NT) STAGE(t + 1, Q ^ 1);

        char* const rb = smem + Q * BUFB;

        // ---- fragments ----
        short8v ah[4], al[4], bh[NF], bl[NF];
#pragma unroll
        for (int i = 0; i < 4; i++) {
            int row = wr * 64 + i * 16 + lrow;
            int slot = (q16 ^ ((row >> 1) & 3)) << 4;
            ah[i] = *(const short8v*)(rb + row * 64 + slot);
            al[i] = *(const short8v*)(rb + 8192 + row * 64 + slot);
        }
#pragma unroll
        for (int j = 0; j < NF; j++) {
            int row = wc * (BN / 2) + j * 16 + lrow;
            int slot = (q16 ^ ((row >> 1) & 3)) << 4;
            bh[j] = *(const short8v*)(rb + 16384 + row * 64 + slot);
            bl[j] = *(const short8v*)(rb + 16384 + BHALF + row * 64 + slot);
        }

        // ---- MFMA: 3-pass split-bf16 ----
#pragma unroll
        for (int i = 0; i < 4; i++)
#pragma unroll
            for (int j = 0; j < NF; j++) {
                acc[i][j] = __builtin_amdgcn_mfma_f32_16x16x32_bf16(ah[i], bh[j], acc[i][j], 0, 0, 0);
                acc[i][j] = __builtin_amdgcn_mfma_f32_16x16x32_bf16(ah[i], bl[j], acc[i][j], 0, 0, 0);
                acc[i][j] = __builtin_amdgcn_mfma_f32_16x16x32_bf16(al[i], bh[j], acc[i][j], 0, 0, 0);
            }

        __syncthreads();
    }

    // ---- epilogue ----
    float* gul = (float*)smem;   // FUSE: [128][68] fp32 tile (34816 B); loop is done with smem
#pragma unroll
    for (int j = 0; j < NF; j++) {
        int col = bn * BN + wc * (BN / 2) + j * 16 + lrow;
        float bi = bias[col];
        float sc = scale ? scale[col] : 1.0f;
#pragma unroll
        for (int i = 0; i < 4; i++) {
            int r0 = bm * BM + wr * 64 + i * 16 + q16 * 4;
#pragma unroll
            for (int reg = 0; reg < 4; reg++) {
                float v = (acc[i][j][reg] + bi) * sc;
                C[(size_t)(r0 + reg) * N + col] = v;
                if constexpr (FUSE) {
                    int lr = wr * 64 + i * 16 + q16 * 4 + reg;
                    int lc = wc * (BN / 2) + j * 16 + lrow;
                    gul[lr * 68 + lc] = v;
                }
            }
        }
    }

    if constexpr (FUSE) {
        __syncthreads();
        // 256 threads: one (chunk, channel) scan each. BM=128 -> 4 chunks of 32.
        const int lc = tid >> 6;          // local chunk 0..3
        const int ch = tid & 63;          // local channel 0..63
        const int gcol = bn * BN + ch;
        const float d = sigmoidf_dev(lam[gcol]);
        float h = 0.0f;
#pragma unroll
        for (int rr = 0; rr < LCH; rr++)
            h = fmaf(d, h, gul[(lc * LCH + rr) * 68 + ch]);
        const int row0 = bm * BM;
        const int b    = row0 >> 12;                       // /4096
        const int gch  = ((row0 & 4095) >> 5) + lc;        // global chunk in [0,128)
        csum[((size_t)b * NCH + gch) * DS + gcol] = h;
    }
#undef STAGE
}

// ---------------- scan kernels ----------------
__global__ __launch_bounds__(256) void carry_scan(
    const float* __restrict__ csum, const float* __restrict__ state,
    const float* __restrict__ lam, float* __restrict__ carry, float* __restrict__ hlast)
{
    const int s = threadIdx.x;
    const int b = blockIdx.x;
    const float d = sigmoidf_dev(lam[s]);
    float dL = d;
#pragma unroll
    for (int i = 0; i < 5; i++) dL *= dL;   // d^32
    float H = state[(size_t)b * DS + s];
#pragma unroll 8
    for (int k = 0; k < NCH; k++) {
        carry[((size_t)b * NCH + k) * DS + s] = H;
        H = fmaf(dL, H, csum[((size_t)b * NCH + k) * DS + s]);
    }
    hlast[(size_t)b * DS + s] = H;
}

__global__ __launch_bounds__(256) void scan_final(
    const float* __restrict__ gu, const float* __restrict__ lam,
    const float* __restrict__ carry,
    unsigned short* __restrict__ hhi, unsigned short* __restrict__ hlo)
{
    const int s = threadIdx.x;
    const int chunk = blockIdx.x;
    const int b = blockIdx.y;
    const float d = sigmoidf_dev(lam[s]);
    const size_t base = ((size_t)b * TT + (size_t)chunk * LCH) * DS + s;
    const float* p = gu + base;
    unsigned short* ph = hhi + base;
    unsigned short* pl = hlo + base;
    float h = carry[((size_t)b * NCH + chunk) * DS + s];
#pragma unroll
    for (int t = 0; t < LCH; t++) {
        h = fmaf(d, h, p[(size_t)t * DS]);
        unsigned short hi, lo;
        split_bf16(h, hi, lo);
        ph[(size_t)t * DS] = hi;
        pl[(size_t)t * DS] = lo;
    }
}

extern "C" void kernel_launch(void* const* d_in, const int* in_sizes, int n_in,
                              void* d_out, int out_size, void* d_ws, size_t ws_size,
                              hipStream_t stream) {
    const float* x     = (const float*)d_in[0];
    const float* state = (const float*)d_in[1];
    const float* W_in  = (const float*)d_in[2];
    const float* b_in  = (const float*)d_in[3];
    const float* lam   = (const float*)d_in[4];
    const float* gamma = (const float*)d_in[5];
    const float* W_out = (const float*)d_in[6];
    const float* b_out = (const float*)d_in[7];

    float* y     = (float*)d_out;
    float* hlast = y + (size_t)MROWS * DM;

    char* ws = (char*)d_ws;
    const size_t MB = 1024 * 1024;
    float*          gu    = (float*)(ws);                        // 16 MB
    float*          csum  = (float*)(ws + 16 * MB);              // 512 KB
    float*          carry = (float*)(ws + 16 * MB + 512 * 1024); // 512 KB
    unsigned short* hhi   = (unsigned short*)(ws + 17 * MB);     // 8 MB
    unsigned short* hlo   = (unsigned short*)(ws + 25 * MB);     // 8 MB
    unsigned short* w1hi  = (unsigned short*)(ws + 33 * MB);     // [DS][DM]
    unsigned short* w1lo  = (unsigned short*)(ws + 33 * MB + 512 * 1024);
    unsigned short* w2hi  = (unsigned short*)(ws + 34 * MB);     // [DM][DS]
    unsigned short* w2lo  = (unsigned short*)(ws + 34 * MB + 512 * 1024);
    unsigned short* xhi   = (unsigned short*)(ws + 35 * MB);     // 32 MB [M][DM]
    unsigned short* xlo   = (unsigned short*)(ws + 67 * MB);     // 32 MB

    split_weights<<<dim3(2048), dim3(256), 0, stream>>>(W_in, w1hi, w1lo, W_out, w2hi, w2lo);

    // x -> bf16 hi/lo (once; removes all split VALU from GEMM1's inner loop)
    split_x<<<dim3((MROWS * DM) / (256 * 8)), dim3(256), 0, stream>>>(x, xhi, xlo);

    // GEMM1 (+fused chunk-partial scan): gu = gamma * (x @ W_in + b_in), csum per chunk
    // [16384 x 256], K=1024, BN=64 -> grid 512
    mfma_gemm<64, true><<<dim3((MROWS / BM) * (DS / 64)), dim3(256), 0, stream>>>(
        xhi, xlo, w1hi, w1lo, gu, MROWS, DS, DM, DS / 64, b_in, gamma, lam, csum);

    carry_scan<<<dim3(BB), dim3(256), 0, stream>>>(csum, state, lam, carry, hlast);
    scan_final<<<dim3(NCH, BB), dim3(256), 0, stream>>>(gu, lam, carry, hhi, hlo);

    // GEMM2: y = h @ W_out + b_out  [16384 x 1024], K=256, BN=128 -> grid 1024
    mfma_gemm<128, false><<<dim3((MROWS / BM) * (DM / 128)), dim3(256), 0, stream>>>(
        hhi, hlo, w2hi, w2lo, y, MROWS, DM, DS, DM / 128, b_out, nullptr, nullptr, nullptr);
}

// Round 7
// 74.439 us; speedup vs baseline: 1.4687x; 1.4687x over previous
//
#include <hip/hip_runtime.h>
#include <hip/hip_bf16.h>
#include <math.h>

// Problem dims (fixed)
#define BB 4
#define TT 4096
#define DM 1024
#define DS 256
#define MROWS (BB*TT)        // 16384

// Scan chunking
#define LCH 32
#define NCH (TT/LCH)         // 128

#define BM 128
#define BK 64

typedef __attribute__((ext_vector_type(8))) _Float16 half8v;
typedef __attribute__((ext_vector_type(4))) float float4v;

__device__ __forceinline__ float sigmoidf_dev(float x) {
    return 1.0f / (1.0f + expf(-x));
}

// async global->LDS, 16 bytes per lane; dest linear (uniform + lane*16)
__device__ __forceinline__ void gload16(const void* g, void* l) {
    __builtin_amdgcn_global_load_lds(
        (const __attribute__((address_space(1))) void*)g,
        (__attribute__((address_space(3))) void*)l, 16, 0, 0);
}

// ---------------- weights -> fp16, transposed to [N][K] ----------------
__global__ __launch_bounds__(256) void cvt_weights(
    const float* __restrict__ W1, _Float16* __restrict__ T1,
    const float* __restrict__ W2, _Float16* __restrict__ T2)
{
    const int half = blockIdx.x >> 10;                   // 0: W_in, 1: W_out
    int idx = (blockIdx.x & 1023) * 256 + threadIdx.x;   // over N*K = 262144
    const float* W = half ? W2 : W1;
    _Float16* T = half ? T2 : T1;
    const int K = half ? DS : DM;
    const int N = half ? DM : DS;
    int n = idx / K, k = idx - n * K;
    T[idx] = (_Float16)W[(size_t)k * N + n];
}

// ---------------- x -> fp16 ----------------
__global__ __launch_bounds__(256) void cvt_x(
    const float* __restrict__ x, _Float16* __restrict__ xf)
{
    size_t u = (size_t)blockIdx.x * 256 + threadIdx.x;   // unit = 8 elems
    const float* p = x + u * 8;
    float4 a = *(const float4*)p;
    float4 b = *(const float4*)(p + 4);
    half8v h;
    h[0] = (_Float16)a.x; h[1] = (_Float16)a.y; h[2] = (_Float16)a.z; h[3] = (_Float16)a.w;
    h[4] = (_Float16)b.x; h[5] = (_Float16)b.y; h[6] = (_Float16)b.z; h[7] = (_Float16)b.w;
    *(half8v*)(xf + u * 8) = h;
}

// ---------------- fp16 MFMA GEMM ----------------
// C[M][N] = (A[M][K] @ Bt[N][K]^T + bias[n]) * scale[n]
// 256 threads, 4 waves 2x2; wave tile 64 x (BN/2); BK=64 (8 x 16B chunks/row).
// LDS slot mapping (both tiles): slot c = row*8 + ch' holds global chunk ch'^(row&7).
//   -> global source pre-swizzled (row-block reads stay 128B-coalesced),
//   -> frag ds_read_b128: every 8-lane group covers 8 distinct 16B slots: conflict-free.
// FUSE: epilogue also computes per-chunk scan partials csum (BM=128 = 4 chunks of 32).
template<int BN, bool FUSE>
__global__ __launch_bounds__(256) void gemm_f16(
    const _Float16* __restrict__ A, const _Float16* __restrict__ Bt,
    float* __restrict__ C, int M, int N, int K, int GN,
    const float* __restrict__ bias, const float* __restrict__ scale,
    const float* __restrict__ lam, float* __restrict__ csum)
{
    constexpr int WCOLS = BN / 2;                 // per-wave cols
    constexpr int NF    = WCOLS / 16;             // B frags per wave
    constexpr int ABYTES = BM * BK * 2;           // 16384
    constexpr int BBYTES = BN * BK * 2;
    constexpr int BUFB   = ABYTES + BBYTES;
    constexpr int SMSZ   = (2 * BUFB > 34816) ? 2 * BUFB : 34816;
    __shared__ char smem[SMSZ];

    // XCD-aware block swizzle (grid % 8 == 0)
    const int nwg = gridDim.x;
    const int bid = blockIdx.x;
    const int wgid = (bid & 7) * (nwg >> 3) + (bid >> 3);
    const int bm = wgid / GN;
    const int bn = wgid - bm * GN;

    const int tid  = threadIdx.x;
    const int lane = tid & 63;
    const int wv   = tid >> 6;
    const int wr   = wv >> 1;            // wave row: 0..1 (64 rows)
    const int wc   = wv & 1;             // wave col: 0..1 (WCOLS cols)
    const int lrow = lane & 15;
    const int q16  = lane >> 4;          // 0..3

    const int NT = K / BK;
    float4v acc[4][NF] = {};

#define STAGE(T, Q)                                                               \
    do {                                                                          \
        const int k0_ = (T) * BK;                                                 \
        char* base_ = smem + (Q) * BUFB;                                          \
        _Pragma("unroll")                                                         \
        for (int p = 0; p < 4; p++) {                                             \
            int c = tid + p * 256, r = c >> 3, chp = c & 7;                       \
            const _Float16* g = A + (size_t)(bm * BM + r) * K + k0_               \
                                  + ((chp ^ (r & 7)) << 3);                       \
            gload16(g, base_ + c * 16);                                           \
        }                                                                         \
        _Pragma("unroll")                                                         \
        for (int p = 0; p < BN / 32; p++) {                                       \
            int c = tid + p * 256, r = c >> 3, chp = c & 7;                       \
            const _Float16* g = Bt + (size_t)(bn * BN + r) * K + k0_              \
                                   + ((chp ^ (r & 7)) << 3);                      \
            gload16(g, base_ + ABYTES + c * 16);                                  \
        }                                                                         \
    } while (0)

    STAGE(0, 0);
    __syncthreads();

    for (int t = 0; t < NT; ++t) {
        const int Q = t & 1;
        if (t + 1 < NT) STAGE(t + 1, Q ^ 1);

        char* const rb = smem + Q * BUFB;

        // ---- fragments (conflict-free swizzled reads) ----
        half8v a[4][2], b[NF][2];
#pragma unroll
        for (int i = 0; i < 4; i++) {
            int row = wr * 64 + i * 16 + lrow;
#pragma unroll
            for (int ss = 0; ss < 2; ss++) {
                int ch = ss * 4 + q16;
                a[i][ss] = *(const half8v*)(rb + ((row * 8 + (ch ^ (row & 7))) << 4));
            }
        }
#pragma unroll
        for (int j = 0; j < NF; j++) {
            int row = wc * WCOLS + j * 16 + lrow;
#pragma unroll
            for (int ss = 0; ss < 2; ss++) {
                int ch = ss * 4 + q16;
                b[j][ss] = *(const half8v*)(rb + ABYTES + ((row * 8 + (ch ^ (row & 7))) << 4));
            }
        }

        // ---- MFMA: single-pass fp16 ----
#pragma unroll
        for (int ss = 0; ss < 2; ss++)
#pragma unroll
            for (int i = 0; i < 4; i++)
#pragma unroll
                for (int j = 0; j < NF; j++)
                    acc[i][j] = __builtin_amdgcn_mfma_f32_16x16x32_f16(a[i][ss], b[j][ss], acc[i][j], 0, 0, 0);

        __syncthreads();
    }

    // ---- epilogue ----
    float* gul = (float*)smem;   // FUSE: [128][68] fp32 tile (34816 B)
#pragma unroll
    for (int j = 0; j < NF; j++) {
        int col = bn * BN + wc * WCOLS + j * 16 + lrow;
        float bi = bias[col];
        float sc = scale ? scale[col] : 1.0f;
#pragma unroll
        for (int i = 0; i < 4; i++) {
            int r0 = bm * BM + wr * 64 + i * 16 + q16 * 4;
#pragma unroll
            for (int reg = 0; reg < 4; reg++) {
                float v = (acc[i][j][reg] + bi) * sc;
                C[(size_t)(r0 + reg) * N + col] = v;
                if constexpr (FUSE) {
                    int lr = wr * 64 + i * 16 + q16 * 4 + reg;
                    int lc = wc * WCOLS + j * 16 + lrow;
                    gul[lr * 68 + lc] = v;
                }
            }
        }
    }

    if constexpr (FUSE) {
        __syncthreads();
        // 256 threads: one (chunk, channel) scan each; BM=128 -> 4 chunks of 32.
        const int lc = tid >> 6;          // local chunk 0..3
        const int ch = tid & 63;          // local channel 0..63
        const int gcol = bn * BN + ch;
        const float d = sigmoidf_dev(lam[gcol]);
        float h = 0.0f;
#pragma unroll
        for (int rr = 0; rr < LCH; rr++)
            h = fmaf(d, h, gul[(lc * LCH + rr) * 68 + ch]);
        const int row0 = bm * BM;
        const int b    = row0 >> 12;                       // /4096
        const int gch  = ((row0 & 4095) >> 5) + lc;        // global chunk in [0,128)
        csum[((size_t)b * NCH + gch) * DS + gcol] = h;
    }
#undef STAGE
}

// ---------------- scan kernels ----------------
__global__ __launch_bounds__(256) void carry_scan(
    const float* __restrict__ csum, const float* __restrict__ state,
    const float* __restrict__ lam, float* __restrict__ carry, float* __restrict__ hlast)
{
    const int s = threadIdx.x;
    const int b = blockIdx.x;
    const float d = sigmoidf_dev(lam[s]);
    float dL = d;
#pragma unroll
    for (int i = 0; i < 5; i++) dL *= dL;   // d^32
    float H = state[(size_t)b * DS + s];
#pragma unroll 8
    for (int k = 0; k < NCH; k++) {
        carry[((size_t)b * NCH + k) * DS + s] = H;
        H = fmaf(dL, H, csum[((size_t)b * NCH + k) * DS + s]);
    }
    hlast[(size_t)b * DS + s] = H;
}

// recompute with carry; emit h as fp16 (feeds GEMM2 directly)
__global__ __launch_bounds__(256) void scan_final(
    const float* __restrict__ gu, const float* __restrict__ lam,
    const float* __restrict__ carry, _Float16* __restrict__ hf)
{
    const int s = threadIdx.x;
    const int chunk = blockIdx.x;
    const int b = blockIdx.y;
    const float d = sigmoidf_dev(lam[s]);
    const size_t base = ((size_t)b * TT + (size_t)chunk * LCH) * DS + s;
    const float* p = gu + base;
    _Float16* ph = hf + base;
    float h = carry[((size_t)b * NCH + chunk) * DS + s];
#pragma unroll
    for (int t = 0; t < LCH; t++) {
        h = fmaf(d, h, p[(size_t)t * DS]);
        ph[(size_t)t * DS] = (_Float16)h;
    }
}

extern "C" void kernel_launch(void* const* d_in, const int* in_sizes, int n_in,
                              void* d_out, int out_size, void* d_ws, size_t ws_size,
                              hipStream_t stream) {
    const float* x     = (const float*)d_in[0];
    const float* state = (const float*)d_in[1];
    const float* W_in  = (const float*)d_in[2];
    const float* b_in  = (const float*)d_in[3];
    const float* lam   = (const float*)d_in[4];
    const float* gamma = (const float*)d_in[5];
    const float* W_out = (const float*)d_in[6];
    const float* b_out = (const float*)d_in[7];

    float* y     = (float*)d_out;
    float* hlast = y + (size_t)MROWS * DM;

    char* ws = (char*)d_ws;
    const size_t MB = 1024 * 1024;
    float*     gu    = (float*)(ws);                         // 16 MB
    float*     csum  = (float*)(ws + 16 * MB);               // 512 KB
    float*     carry = (float*)(ws + 16 * MB + 512 * 1024);  // 512 KB
    _Float16*  hf    = (_Float16*)(ws + 17 * MB);            // 8 MB  [M][DS]
    _Float16*  w1t   = (_Float16*)(ws + 25 * MB);            // 512 KB [DS][DM]
    _Float16*  w2t   = (_Float16*)(ws + 25 * MB + 512 * 1024); // 512 KB [DM][DS]
    _Float16*  xf    = (_Float16*)(ws + 26 * MB);            // 32 MB [M][DM]

    cvt_weights<<<dim3(2048), dim3(256), 0, stream>>>(W_in, w1t, W_out, w2t);
    cvt_x<<<dim3((MROWS * DM) / (256 * 8)), dim3(256), 0, stream>>>(x, xf);

    // GEMM1 (+fused chunk-partial scan): gu = gamma * (x @ W_in + b_in)
    // [16384 x 256], K=1024, BN=64 -> grid 512
    gemm_f16<64, true><<<dim3((MROWS / BM) * (DS / 64)), dim3(256), 0, stream>>>(
        xf, w1t, gu, MROWS, DS, DM, DS / 64, b_in, gamma, lam, csum);

    carry_scan<<<dim3(BB), dim3(256), 0, stream>>>(csum, state, lam, carry, hlast);
    scan_final<<<dim3(NCH, BB), dim3(256), 0, stream>>>(gu, lam, carry, hf);

    // GEMM2: y = h @ W_out + b_out  [16384 x 1024], K=256, BN=128 -> grid 1024
    gemm_f16<128, false><<<dim3((MROWS / BM) * (DM / 128)), dim3(256), 0, stream>>>(
        hf, w2t, y, MROWS, DM, DS, DM / 128, b_out, nullptr, nullptr, nullptr);
}